// Round 4
// baseline (1077.321 us; speedup 1.0000x reference)
//
#include <hip/hip_runtime.h>
#include <hip/hip_bf16.h>

#define Nn 100000
#define Ee 1600000
#define Hh 128
#define Gg 1000
#define EPSb 1e-5f

#define SCAN_CHUNK 1024
#define NB_SCAN 98          // ceil(100000/1024)
#define AGG_BLOCKS 2048     // 8 slices x 256 node-blocks
#define GEMM_BLOCKS 782     // ceil(100000/128)

typedef unsigned int uint;
typedef unsigned long long u64;
typedef short short8 __attribute__((ext_vector_type(8)));
typedef float floatx4 __attribute__((ext_vector_type(4)));

// round-to-nearest-even f32 -> bf16 (as low 16 bits of return)
static __device__ __forceinline__ uint bf16rne(float f) {
    uint u = __float_as_uint(f);
    return (u + 0x7fffu + ((u >> 16) & 1u)) >> 16;
}
static __device__ __forceinline__ float bflo(uint u) { return __uint_as_float(u << 16); }
static __device__ __forceinline__ float bfhi(uint u) { return __uint_as_float(u & 0xffff0000u); }

// Slice-major activation layout: buf[slice][node][8 uints], slice = f>>4,
// uint j within slice packs features s*16+2j (lo), s*16+2j+1 (hi).

// ---------------- graph preprocessing ----------------

__global__ void k_init(int* __restrict__ deg, int* __restrict__ cursor,
                       float* __restrict__ colsum) {
    int i = blockIdx.x * blockDim.x + threadIdx.x;
    if (i < Nn) { deg[i] = 1; cursor[i] = 0; }
    if (i < 256) colsum[i] = 0.f;
}

__global__ void k_deg(const int* __restrict__ dst, int* __restrict__ deg) {
    int i = blockIdx.x * blockDim.x + threadIdx.x;
    if (i < Ee) atomicAdd(&deg[dst[i]], 1);
}

__global__ void k_dinv(const int* __restrict__ deg, float* __restrict__ dinv) {
    int i = blockIdx.x * blockDim.x + threadIdx.x;
    if (i < Nn) dinv[i] = rsqrtf((float)deg[i]);
}

__global__ void k_scan1(const int* __restrict__ deg, int* __restrict__ bsum) {
    __shared__ int ls[256];
    int t = threadIdx.x;
    int base = blockIdx.x * SCAN_CHUNK + t * 4;
    int s = 0;
#pragma unroll
    for (int j = 0; j < 4; ++j) { int i = base + j; if (i < Nn) s += deg[i]; }
    ls[t] = s;
    __syncthreads();
    for (int off = 128; off; off >>= 1) {
        if (t < off) ls[t] += ls[t + off];
        __syncthreads();
    }
    if (t == 0) bsum[blockIdx.x] = ls[0];
}

__global__ void k_scan2(int* __restrict__ bsum, int nb) {
    int acc = 0;
    for (int b = 0; b < nb; ++b) { int v = bsum[b]; bsum[b] = acc; acc += v; }
}

__global__ void k_scan3(const int* __restrict__ deg, const int* __restrict__ bsum,
                        int* __restrict__ offs) {
    __shared__ int ls[256];
    int t = threadIdx.x;
    int base = blockIdx.x * SCAN_CHUNK + t * 4;
    int d[4]; int s = 0;
#pragma unroll
    for (int j = 0; j < 4; ++j) {
        int i = base + j;
        d[j] = (i < Nn) ? deg[i] : 0;
        s += d[j];
    }
    ls[t] = s;
    __syncthreads();
    for (int off = 1; off < 256; off <<= 1) {
        int u = (t >= off) ? ls[t - off] : 0;
        __syncthreads();
        ls[t] += u;
        __syncthreads();
    }
    int run = bsum[blockIdx.x] + ls[t] - s;   // exclusive prefix for this thread
#pragma unroll
    for (int j = 0; j < 4; ++j) {
        int i = base + j;
        if (i < Nn) offs[i] = run;
        run += d[j];
    }
    if (blockIdx.x == 0 && t == 0) offs[Nn] = Ee + Nn;
}

__global__ void k_fill(const int* __restrict__ src, const int* __restrict__ dst,
                       const int* __restrict__ offs, int* __restrict__ cursor,
                       const float* __restrict__ dinv,
                       int2* __restrict__ adj) {
    int i = blockIdx.x * blockDim.x + threadIdx.x;
    if (i >= Ee + Nn) return;
    int s, d;
    if (i < Ee) { s = src[i]; d = dst[i]; }
    else        { s = d = i - Ee; }
    int pos = offs[d] + atomicAdd(&cursor[d], 1);
    adj[pos] = make_int2(s, __float_as_int(dinv[s] * dinv[d]));
}

// ------------- W conversion: Wtp[n][k/2] = packed bf16 of W[k][n],W[k+1][n] ----

__global__ void k_wconv(const float* __restrict__ W, uint* __restrict__ Wtp) {
    int idx = blockIdx.x * blockDim.x + threadIdx.x;   // 8192
    if (idx >= 128 * 64) return;
    int n = idx >> 6, ku = idx & 63;
    uint lo = bf16rne(W[(size_t)(2 * ku) * 128 + n]);
    uint hi = bf16rne(W[(size_t)(2 * ku + 1) * 128 + n]);
    Wtp[(size_t)n * 64 + ku] = lo | (hi << 16);
}

// ---------------- MFMA GEMM: tmp(bf16, slice-major) = act(in) @ W ----------
// mode 0: in = fp32 x (row-major), identity activation.
// mode 1: in = slice-major packed-bf16 agg, activation = relu(v*scale+shift).

__global__ __launch_bounds__(256) void k_gemm(
    const float* __restrict__ inf, const uint* __restrict__ inb,
    const uint* __restrict__ Wtp,
    const float* __restrict__ scale, const float* __restrict__ shift,
    uint* __restrict__ outb, int mode) {
    __shared__ uint XT[128][64];
    __shared__ uint WT[128][64];
    int t = threadIdx.x;
    int rowBase = blockIdx.x * 128;
    int r = t >> 1, half = t & 1;

    {   // stage activations
        int gr = rowBase + r;
        int grc = gr < Nn ? gr : Nn - 1;
        if (mode == 0) {
            const float* sp = inf + (size_t)grc * 128 + half * 64;
#pragma unroll
            for (int q = 0; q < 8; ++q) {
                float4 v0 = *(const float4*)(sp + q * 8);
                float4 v1 = *(const float4*)(sp + q * 8 + 4);
                uint4 o;
                o.x = bf16rne(v0.x) | (bf16rne(v0.y) << 16);
                o.y = bf16rne(v0.z) | (bf16rne(v0.w) << 16);
                o.z = bf16rne(v1.x) | (bf16rne(v1.y) << 16);
                o.w = bf16rne(v1.z) | (bf16rne(v1.w) << 16);
                int g = half * 8 + q;
                *(uint4*)&XT[r][(g ^ (r & 7)) << 2] = o;
            }
        } else {
#pragma unroll
            for (int q = 0; q < 8; ++q) {
                int sl = half * 4 + (q >> 1);
                uint4 v = *(const uint4*)(inb + ((size_t)sl * Nn + grc) * 8 + (q & 1) * 4);
                int fb = half * 64 + q * 8;
                float4 s0 = *(const float4*)(scale + fb);
                float4 s1 = *(const float4*)(scale + fb + 4);
                float4 h0 = *(const float4*)(shift + fb);
                float4 h1 = *(const float4*)(shift + fb + 4);
                float a0 = fmaxf(fmaf(bflo(v.x), s0.x, h0.x), 0.f);
                float a1 = fmaxf(fmaf(bfhi(v.x), s0.y, h0.y), 0.f);
                float a2 = fmaxf(fmaf(bflo(v.y), s0.z, h0.z), 0.f);
                float a3 = fmaxf(fmaf(bfhi(v.y), s0.w, h0.w), 0.f);
                float a4 = fmaxf(fmaf(bflo(v.z), s1.x, h1.x), 0.f);
                float a5 = fmaxf(fmaf(bfhi(v.z), s1.y, h1.y), 0.f);
                float a6 = fmaxf(fmaf(bflo(v.w), s1.z, h1.z), 0.f);
                float a7 = fmaxf(fmaf(bfhi(v.w), s1.w, h1.w), 0.f);
                uint4 o;
                o.x = bf16rne(a0) | (bf16rne(a1) << 16);
                o.y = bf16rne(a2) | (bf16rne(a3) << 16);
                o.z = bf16rne(a4) | (bf16rne(a5) << 16);
                o.w = bf16rne(a6) | (bf16rne(a7) << 16);
                int g = half * 8 + q;
                *(uint4*)&XT[r][(g ^ (r & 7)) << 2] = o;
            }
        }
    }
    {   // stage W^T (already packed bf16)
        const uint* sp = Wtp + (size_t)r * 64 + half * 32;
#pragma unroll
        for (int q = 0; q < 8; ++q) {
            uint4 v = *(const uint4*)(sp + q * 4);
            int g = half * 8 + q;
            *(uint4*)&WT[r][(g ^ (r & 7)) << 2] = v;
        }
    }
    __syncthreads();

    int l = t & 63, w = t >> 6;
    int nb = (w >> 1) * 64;       // node-tile base
    int fb2 = (w & 1) * 64;       // feature-tile base
    int lr = l & 15, lk = l >> 4;
    floatx4 zero = {0.f, 0.f, 0.f, 0.f};
    floatx4 acc[4][4];
#pragma unroll
    for (int mi = 0; mi < 4; ++mi)
#pragma unroll
        for (int ni = 0; ni < 4; ++ni) acc[mi][ni] = zero;

#pragma unroll
    for (int kc = 0; kc < 4; ++kc) {
        short8 xf[4], wf[4];
        int g = kc * 4 + lk;
#pragma unroll
        for (int mi = 0; mi < 4; ++mi) {
            int rr = nb + mi * 16 + lr;
            xf[mi] = *(const short8*)&XT[rr][(g ^ (rr & 7)) << 2];
        }
#pragma unroll
        for (int ni = 0; ni < 4; ++ni) {
            int rr = fb2 + ni * 16 + lr;
            wf[ni] = *(const short8*)&WT[rr][(g ^ (rr & 7)) << 2];
        }
#pragma unroll
        for (int mi = 0; mi < 4; ++mi)
#pragma unroll
            for (int ni = 0; ni < 4; ++ni)
                acc[mi][ni] = __builtin_amdgcn_mfma_f32_16x16x32_bf16(
                    wf[ni], xf[mi], acc[mi][ni], 0, 0, 0);
    }

    // epilogue: D col(lane&15)=node, row((lane>>4)*4+reg)=feature
#pragma unroll
    for (int mi = 0; mi < 4; ++mi) {
        int node = rowBase + nb + mi * 16 + lr;
        if (node < Nn) {
#pragma unroll
            for (int ni = 0; ni < 4; ++ni) {
                int slice = (fb2 >> 4) + ni;
                uint2 o;
                o.x = bf16rne(acc[mi][ni][0]) | (bf16rne(acc[mi][ni][1]) << 16);
                o.y = bf16rne(acc[mi][ni][2]) | (bf16rne(acc[mi][ni][3]) << 16);
                *(uint2*)(outb + ((size_t)slice * Nn + node) * 8 + lk * 2) = o;
            }
        }
    }
}

// ------- aggregation (XCD feature-sharded): agg[d] = sum_e w*h[src] + bias ----
// block b -> slice s = b&7 (round-robins with XCD); wave = one dst node;
// 8 lane-groups x 8 edges in flight, each group gathers 32B slice of h[src];
// shfl_xor butterfly (8/16/32) reduces groups. adj streamed nontemporally.

__global__ __launch_bounds__(256) void k_agg(
    const uint* __restrict__ hs, const int* __restrict__ offs,
    const int2* __restrict__ adj,
    const float* __restrict__ bias, uint* __restrict__ aggs,
    float* __restrict__ colsum) {
    __shared__ float ls[32];
    int tid = threadIdx.x;
    if (tid < 32) ls[tid] = 0.f;
    __syncthreads();
    int s = blockIdx.x & 7;
    int nb = blockIdx.x >> 3;
    int wv = tid >> 6;
    int lane = tid & 63;
    int grp = lane >> 3;
    int col = lane & 7;
    int f0 = s * 16 + col * 2;
    float b0 = bias[f0], b1 = bias[f0 + 1];
    const uint* hbase = hs + (size_t)s * Nn * 8;
    uint* abase = aggs + (size_t)s * Nn * 8;
    const u64* adj8 = (const u64*)adj;
    float ps0 = 0.f, ps1 = 0.f, pq0 = 0.f, pq1 = 0.f;
    for (int d = nb * 4 + wv; d < Nn; d += 1024) {
        int beg = offs[d], end = offs[d + 1];
        float a0 = 0.f, a1 = 0.f;
        int nfull = (end - beg) & ~7;
        int iend = beg + nfull;
        for (int i = beg; i < iend; i += 8) {
            u64 e = __builtin_nontemporal_load(&adj8[i + grp]);
            int src = (int)(e & 0xffffffffu);
            float w = __uint_as_float((uint)(e >> 32));
            uint hv = hbase[(size_t)src * 8 + col];
            a0 = fmaf(w, bflo(hv), a0);
            a1 = fmaf(w, bfhi(hv), a1);
        }
        int i = iend + grp;
        if (i < end) {
            u64 e = __builtin_nontemporal_load(&adj8[i]);
            int src = (int)(e & 0xffffffffu);
            float w = __uint_as_float((uint)(e >> 32));
            uint hv = hbase[(size_t)src * 8 + col];
            a0 = fmaf(w, bflo(hv), a0);
            a1 = fmaf(w, bfhi(hv), a1);
        }
#pragma unroll
        for (int m = 8; m < 64; m <<= 1) {
            a0 += __shfl_xor(a0, m);
            a1 += __shfl_xor(a1, m);
        }
        a0 += b0; a1 += b1;
        if (grp == 0) {
            abase[(size_t)d * 8 + col] = bf16rne(a0) | (bf16rne(a1) << 16);
            ps0 += a0; pq0 += a0 * a0;
            ps1 += a1; pq1 += a1 * a1;
        }
    }
    if (grp == 0) {
        atomicAdd(&ls[col * 2], ps0);
        atomicAdd(&ls[col * 2 + 1], ps1);
        atomicAdd(&ls[16 + col * 2], pq0);
        atomicAdd(&ls[16 + col * 2 + 1], pq1);
    }
    __syncthreads();
    if (tid < 16)      atomicAdd(&colsum[s * 16 + tid], ls[tid]);
    else if (tid < 32) atomicAdd(&colsum[128 + s * 16 + (tid - 16)], ls[tid]);
}

// ---------------- BN finalize: scale/shift, re-zero accumulators ----------

__global__ void k_bnfinal(float* __restrict__ colsum,
                          const float* __restrict__ g, const float* __restrict__ be,
                          float* __restrict__ scale, float* __restrict__ shift) {
    int t = threadIdx.x;  // 128
    float s = colsum[t], q = colsum[128 + t];
    float m = s * (1.0f / Nn);
    float var = q * (1.0f / Nn) - m * m;
    float istd = rsqrtf(var + EPSb);
    float sc = istd * g[t];
    scale[t] = sc;
    shift[t] = fmaf(-m, sc, be[t]);
    colsum[t] = 0.f;
    colsum[128 + t] = 0.f;
}

// ---------------- pool + linear (slice-major agg) -------------------------

__global__ __launch_bounds__(256) void k_pool(
    const uint* __restrict__ agg, const int* __restrict__ batch,
    const float* __restrict__ scale, const float* __restrict__ shift,
    const float* __restrict__ Wl, const float* __restrict__ bl,
    float* __restrict__ out) {
    int lane = threadIdx.x & 63;
    int g = (blockIdx.x * blockDim.x + threadIdx.x) >> 6;
    if (g >= Gg) return;
    int lo = 0, hi = Nn;
    while (lo < hi) { int mid = (lo + hi) >> 1; if (batch[mid] < g) lo = mid + 1; else hi = mid; }
    int beg = lo;
    hi = Nn;
    while (lo < hi) { int mid = (lo + hi) >> 1; if (batch[mid] < g + 1) lo = mid + 1; else hi = mid; }
    int end = lo;
    int sl = lane >> 3, j = lane & 7;
    int c0 = sl * 16 + j * 2;
    const uint* base = agg + (size_t)sl * Nn * 8 + j;
    float sc0 = scale[c0], sh0 = shift[c0];
    float sc1 = scale[c0 + 1], sh1 = shift[c0 + 1];
    float s0 = 0.f, s1 = 0.f;
    for (int n = beg; n < end; ++n) {
        uint v = base[(size_t)n * 8];
        s0 += fmaxf(fmaf(bflo(v), sc0, sh0), 0.f);
        s1 += fmaxf(fmaf(bfhi(v), sc1, sh1), 0.f);
    }
    float inv = 1.0f / fmaxf((float)(end - beg), 1.0f);
    float part = (s0 * inv) * Wl[c0] + (s1 * inv) * Wl[c0 + 1];
#pragma unroll
    for (int off = 32; off; off >>= 1) part += __shfl_down(part, off);
    if (lane == 0) out[g] = part + bl[0];
}

// ---------------- launch --------------------------------------------------

extern "C" void kernel_launch(void* const* d_in, const int* in_sizes, int n_in,
                              void* d_out, int out_size, void* d_ws, size_t ws_size,
                              hipStream_t stream) {
    const float* x   = (const float*)d_in[0];
    const int*   ei  = (const int*)d_in[1];
    const int*   src = ei;
    const int*   dst = ei + Ee;
    const int*   bat = (const int*)d_in[2];
    const float* W1 = (const float*)d_in[3];
    const float* b1 = (const float*)d_in[4];
    const float* g1 = (const float*)d_in[5];
    const float* be1 = (const float*)d_in[6];
    const float* W2 = (const float*)d_in[7];
    const float* b2 = (const float*)d_in[8];
    const float* g2 = (const float*)d_in[9];
    const float* be2 = (const float*)d_in[10];
    const float* W3 = (const float*)d_in[11];
    const float* b3 = (const float*)d_in[12];
    const float* g3 = (const float*)d_in[13];
    const float* be3 = (const float*)d_in[14];
    const float* Wl = (const float*)d_in[15];
    const float* bl = (const float*)d_in[16];
    float* out = (float*)d_out;

    char* w = (char*)d_ws;
    auto alloc = [&](size_t bytes) {
        void* p = (void*)w;
        w += (bytes + 255) & ~(size_t)255;
        return p;
    };
    int*   deg    = (int*)alloc((size_t)Nn * 4);
    int*   cursor = (int*)alloc((size_t)Nn * 4);
    int*   offs   = (int*)alloc((size_t)(Nn + 1) * 4);
    int*   bsum   = (int*)alloc(256 * 4);
    float* dinv   = (float*)alloc((size_t)Nn * 4);
    float* colsum = (float*)alloc(256 * 4);
    float* scale  = (float*)alloc(128 * 4);
    float* shift  = (float*)alloc(128 * 4);
    uint*  Wt1    = (uint*)alloc(128 * 64 * 4);
    uint*  Wt2    = (uint*)alloc(128 * 64 * 4);
    uint*  Wt3    = (uint*)alloc(128 * 64 * 4);
    int2*  adj    = (int2*)alloc((size_t)(Ee + Nn) * 8);
    uint*  tmp    = (uint*)alloc((size_t)Nn * 64 * 4);   // bf16-packed h, slice-major
    uint*  agg    = (uint*)alloc((size_t)Nn * 64 * 4);   // bf16-packed agg, slice-major

    // graph preprocessing + weight conversion
    k_init<<<(Nn + 255) / 256, 256, 0, stream>>>(deg, cursor, colsum);
    k_deg<<<(Ee + 255) / 256, 256, 0, stream>>>(dst, deg);
    k_dinv<<<(Nn + 255) / 256, 256, 0, stream>>>(deg, dinv);
    k_scan1<<<NB_SCAN, 256, 0, stream>>>(deg, bsum);
    k_scan2<<<1, 1, 0, stream>>>(bsum, NB_SCAN);
    k_scan3<<<NB_SCAN, 256, 0, stream>>>(deg, bsum, offs);
    k_fill<<<(Ee + Nn + 255) / 256, 256, 0, stream>>>(src, dst, offs, cursor, dinv, adj);
    k_wconv<<<32, 256, 0, stream>>>(W1, Wt1);
    k_wconv<<<32, 256, 0, stream>>>(W2, Wt2);
    k_wconv<<<32, 256, 0, stream>>>(W3, Wt3);
    // layer 1
    k_gemm<<<GEMM_BLOCKS, 256, 0, stream>>>(x, (const uint*)0, Wt1, scale, shift, tmp, 0);
    k_agg<<<AGG_BLOCKS, 256, 0, stream>>>(tmp, offs, adj, b1, agg, colsum);
    k_bnfinal<<<1, 128, 0, stream>>>(colsum, g1, be1, scale, shift);
    // layer 2
    k_gemm<<<GEMM_BLOCKS, 256, 0, stream>>>((const float*)0, agg, Wt2, scale, shift, tmp, 1);
    k_agg<<<AGG_BLOCKS, 256, 0, stream>>>(tmp, offs, adj, b2, agg, colsum);
    k_bnfinal<<<1, 128, 0, stream>>>(colsum, g2, be2, scale, shift);
    // layer 3
    k_gemm<<<GEMM_BLOCKS, 256, 0, stream>>>((const float*)0, agg, Wt3, scale, shift, tmp, 1);
    k_agg<<<AGG_BLOCKS, 256, 0, stream>>>(tmp, offs, adj, b3, agg, colsum);
    k_bnfinal<<<1, 128, 0, stream>>>(colsum, g3, be3, scale, shift);
    // pool + linear
    k_pool<<<(Gg * 64 + 255) / 256, 256, 0, stream>>>(agg, bat, scale, shift, Wl, bl, out);
}

// Round 5
// 863.490 us; speedup vs baseline: 1.2476x; 1.2476x over previous
//
#include <hip/hip_runtime.h>
#include <hip/hip_bf16.h>

#define Nn 100000
#define Ee 1600000
#define Hh 128
#define Gg 1000
#define EPSb 1e-5f

#define SCAN_CHUNK 1024
#define NB_SCAN 98          // ceil(100000/1024)
#define AGG_BLOCKS 2048     // 8 slices x 256 node-blocks
#define GEMM_BLOCKS 782     // ceil(100000/128)

typedef unsigned int uint;
typedef unsigned long long u64;
typedef short short8 __attribute__((ext_vector_type(8)));
typedef float floatx4 __attribute__((ext_vector_type(4)));

// round-to-nearest-even f32 -> bf16 (as low 16 bits of return)
static __device__ __forceinline__ uint bf16rne(float f) {
    uint u = __float_as_uint(f);
    return (u + 0x7fffu + ((u >> 16) & 1u)) >> 16;
}
static __device__ __forceinline__ float bflo(uint u) { return __uint_as_float(u << 16); }
static __device__ __forceinline__ float bfhi(uint u) { return __uint_as_float(u & 0xffff0000u); }

// Slice-major activation layout: buf[slice][node][8 uints], slice = f>>4,
// uint j within slice packs features s*16+2j (lo), s*16+2j+1 (hi).

// ---------------- graph preprocessing ----------------

__global__ void k_init(int* __restrict__ deg, int* __restrict__ cursor,
                       float* __restrict__ colsum) {
    int i = blockIdx.x * blockDim.x + threadIdx.x;
    if (i < Nn) { deg[i] = 1; cursor[i] = 0; }
    if (i < 256) colsum[i] = 0.f;
}

__global__ void k_deg(const int* __restrict__ dst, int* __restrict__ deg) {
    int i = blockIdx.x * blockDim.x + threadIdx.x;
    if (i < Ee) atomicAdd(&deg[dst[i]], 1);
}

__global__ void k_dinv(const int* __restrict__ deg, float* __restrict__ dinv) {
    int i = blockIdx.x * blockDim.x + threadIdx.x;
    if (i < Nn) dinv[i] = rsqrtf((float)deg[i]);
}

__global__ void k_scan1(const int* __restrict__ deg, int* __restrict__ bsum) {
    __shared__ int ls[256];
    int t = threadIdx.x;
    int base = blockIdx.x * SCAN_CHUNK + t * 4;
    int s = 0;
#pragma unroll
    for (int j = 0; j < 4; ++j) { int i = base + j; if (i < Nn) s += deg[i]; }
    ls[t] = s;
    __syncthreads();
    for (int off = 128; off; off >>= 1) {
        if (t < off) ls[t] += ls[t + off];
        __syncthreads();
    }
    if (t == 0) bsum[blockIdx.x] = ls[0];
}

__global__ void k_scan2(int* __restrict__ bsum, int nb) {
    int acc = 0;
    for (int b = 0; b < nb; ++b) { int v = bsum[b]; bsum[b] = acc; acc += v; }
}

__global__ void k_scan3(const int* __restrict__ deg, const int* __restrict__ bsum,
                        int* __restrict__ offs) {
    __shared__ int ls[256];
    int t = threadIdx.x;
    int base = blockIdx.x * SCAN_CHUNK + t * 4;
    int d[4]; int s = 0;
#pragma unroll
    for (int j = 0; j < 4; ++j) {
        int i = base + j;
        d[j] = (i < Nn) ? deg[i] : 0;
        s += d[j];
    }
    ls[t] = s;
    __syncthreads();
    for (int off = 1; off < 256; off <<= 1) {
        int u = (t >= off) ? ls[t - off] : 0;
        __syncthreads();
        ls[t] += u;
        __syncthreads();
    }
    int run = bsum[blockIdx.x] + ls[t] - s;   // exclusive prefix for this thread
#pragma unroll
    for (int j = 0; j < 4; ++j) {
        int i = base + j;
        if (i < Nn) offs[i] = run;
        run += d[j];
    }
    if (blockIdx.x == 0 && t == 0) offs[Nn] = Ee + Nn;
}

__global__ void k_fill(const int* __restrict__ src, const int* __restrict__ dst,
                       const int* __restrict__ offs, int* __restrict__ cursor,
                       const float* __restrict__ dinv,
                       int2* __restrict__ adj) {
    int i = blockIdx.x * blockDim.x + threadIdx.x;
    if (i >= Ee + Nn) return;
    int s, d;
    if (i < Ee) { s = src[i]; d = dst[i]; }
    else        { s = d = i - Ee; }
    int pos = offs[d] + atomicAdd(&cursor[d], 1);
    adj[pos] = make_int2(s, __float_as_int(dinv[s] * dinv[d]));
}

// ------------- W conversion: Wtp[n][k/2] = packed bf16 of W[k][n],W[k+1][n] ----

__global__ void k_wconv(const float* __restrict__ W, uint* __restrict__ Wtp) {
    int idx = blockIdx.x * blockDim.x + threadIdx.x;   // 8192
    if (idx >= 128 * 64) return;
    int n = idx >> 6, ku = idx & 63;
    uint lo = bf16rne(W[(size_t)(2 * ku) * 128 + n]);
    uint hi = bf16rne(W[(size_t)(2 * ku + 1) * 128 + n]);
    Wtp[(size_t)n * 64 + ku] = lo | (hi << 16);
}

// ---------------- MFMA GEMM: tmp(bf16, slice-major) = act(in) @ W ----------
// mode 0: in = fp32 x (row-major), identity activation.
// mode 1: in = slice-major packed-bf16 agg, activation = relu(v*scale+shift).

__global__ __launch_bounds__(256) void k_gemm(
    const float* __restrict__ inf, const uint* __restrict__ inb,
    const uint* __restrict__ Wtp,
    const float* __restrict__ scale, const float* __restrict__ shift,
    uint* __restrict__ outb, int mode) {
    __shared__ uint XT[128][64];
    __shared__ uint WT[128][64];
    int t = threadIdx.x;
    int rowBase = blockIdx.x * 128;
    int r = t >> 1, half = t & 1;

    {   // stage activations
        int gr = rowBase + r;
        int grc = gr < Nn ? gr : Nn - 1;
        if (mode == 0) {
            const float* sp = inf + (size_t)grc * 128 + half * 64;
#pragma unroll
            for (int q = 0; q < 8; ++q) {
                float4 v0 = *(const float4*)(sp + q * 8);
                float4 v1 = *(const float4*)(sp + q * 8 + 4);
                uint4 o;
                o.x = bf16rne(v0.x) | (bf16rne(v0.y) << 16);
                o.y = bf16rne(v0.z) | (bf16rne(v0.w) << 16);
                o.z = bf16rne(v1.x) | (bf16rne(v1.y) << 16);
                o.w = bf16rne(v1.z) | (bf16rne(v1.w) << 16);
                int g = half * 8 + q;
                *(uint4*)&XT[r][(g ^ (r & 7)) << 2] = o;
            }
        } else {
#pragma unroll
            for (int q = 0; q < 8; ++q) {
                int sl = half * 4 + (q >> 1);
                uint4 v = *(const uint4*)(inb + ((size_t)sl * Nn + grc) * 8 + (q & 1) * 4);
                int fb = half * 64 + q * 8;
                float4 s0 = *(const float4*)(scale + fb);
                float4 s1 = *(const float4*)(scale + fb + 4);
                float4 h0 = *(const float4*)(shift + fb);
                float4 h1 = *(const float4*)(shift + fb + 4);
                float a0 = fmaxf(fmaf(bflo(v.x), s0.x, h0.x), 0.f);
                float a1 = fmaxf(fmaf(bfhi(v.x), s0.y, h0.y), 0.f);
                float a2 = fmaxf(fmaf(bflo(v.y), s0.z, h0.z), 0.f);
                float a3 = fmaxf(fmaf(bfhi(v.y), s0.w, h0.w), 0.f);
                float a4 = fmaxf(fmaf(bflo(v.z), s1.x, h1.x), 0.f);
                float a5 = fmaxf(fmaf(bfhi(v.z), s1.y, h1.y), 0.f);
                float a6 = fmaxf(fmaf(bflo(v.w), s1.z, h1.z), 0.f);
                float a7 = fmaxf(fmaf(bfhi(v.w), s1.w, h1.w), 0.f);
                uint4 o;
                o.x = bf16rne(a0) | (bf16rne(a1) << 16);
                o.y = bf16rne(a2) | (bf16rne(a3) << 16);
                o.z = bf16rne(a4) | (bf16rne(a5) << 16);
                o.w = bf16rne(a6) | (bf16rne(a7) << 16);
                int g = half * 8 + q;
                *(uint4*)&XT[r][(g ^ (r & 7)) << 2] = o;
            }
        }
    }
    {   // stage W^T (already packed bf16)
        const uint* sp = Wtp + (size_t)r * 64 + half * 32;
#pragma unroll
        for (int q = 0; q < 8; ++q) {
            uint4 v = *(const uint4*)(sp + q * 4);
            int g = half * 8 + q;
            *(uint4*)&WT[r][(g ^ (r & 7)) << 2] = v;
        }
    }
    __syncthreads();

    int l = t & 63, w = t >> 6;
    int nb = (w >> 1) * 64;       // node-tile base
    int fb2 = (w & 1) * 64;       // feature-tile base
    int lr = l & 15, lk = l >> 4;
    floatx4 zero = {0.f, 0.f, 0.f, 0.f};
    floatx4 acc[4][4];
#pragma unroll
    for (int mi = 0; mi < 4; ++mi)
#pragma unroll
        for (int ni = 0; ni < 4; ++ni) acc[mi][ni] = zero;

#pragma unroll
    for (int kc = 0; kc < 4; ++kc) {
        short8 xf[4], wf[4];
        int g = kc * 4 + lk;
#pragma unroll
        for (int mi = 0; mi < 4; ++mi) {
            int rr = nb + mi * 16 + lr;
            xf[mi] = *(const short8*)&XT[rr][(g ^ (rr & 7)) << 2];
        }
#pragma unroll
        for (int ni = 0; ni < 4; ++ni) {
            int rr = fb2 + ni * 16 + lr;
            wf[ni] = *(const short8*)&WT[rr][(g ^ (rr & 7)) << 2];
        }
#pragma unroll
        for (int mi = 0; mi < 4; ++mi)
#pragma unroll
            for (int ni = 0; ni < 4; ++ni)
                acc[mi][ni] = __builtin_amdgcn_mfma_f32_16x16x32_bf16(
                    wf[ni], xf[mi], acc[mi][ni], 0, 0, 0);
    }

    // epilogue: D col(lane&15)=node, row((lane>>4)*4+reg)=feature
#pragma unroll
    for (int mi = 0; mi < 4; ++mi) {
        int node = rowBase + nb + mi * 16 + lr;
        if (node < Nn) {
#pragma unroll
            for (int ni = 0; ni < 4; ++ni) {
                int slice = (fb2 >> 4) + ni;
                uint2 o;
                o.x = bf16rne(acc[mi][ni][0]) | (bf16rne(acc[mi][ni][1]) << 16);
                o.y = bf16rne(acc[mi][ni][2]) | (bf16rne(acc[mi][ni][3]) << 16);
                *(uint2*)(outb + ((size_t)slice * Nn + node) * 8 + lk * 2) = o;
            }
        }
    }
}

// ------- aggregation (XCD feature-sharded, group-per-node) ----------------
// block b -> slice s = b&7 (round-robins with XCD -> slice L2-resident).
// wave = 8 lane-groups; group owns one dst node, walks its edge list with
// x4 unrolling (4 adj + 4 h gathers in flight); lane accumulates its own
// 2 features -> no cross-lane reduce. adj streamed nontemporally.

__global__ __launch_bounds__(256) void k_agg(
    const uint* __restrict__ hs, const int* __restrict__ offs,
    const int2* __restrict__ adj,
    const float* __restrict__ bias, uint* __restrict__ aggs,
    float* __restrict__ colsum) {
    __shared__ float ls[32];
    int tid = threadIdx.x;
    if (tid < 32) ls[tid] = 0.f;
    __syncthreads();
    int s = blockIdx.x & 7;
    int nb = blockIdx.x >> 3;        // 0..255
    int wv = tid >> 6;               // 0..3
    int lane = tid & 63;
    int grp = lane >> 3;             // 0..7: node slot
    int col = lane & 7;              // uint within slice
    int f0 = s * 16 + col * 2;
    float b0 = bias[f0], b1 = bias[f0 + 1];
    const uint* hbase = hs + (size_t)s * Nn * 8;
    uint* abase = aggs + (size_t)s * Nn * 8;
    const u64* adj8 = (const u64*)adj;
    float ps0 = 0.f, ps1 = 0.f, pq0 = 0.f, pq1 = 0.f;
    for (int d = nb * 32 + wv * 8 + grp; d < Nn; d += 8192) {
        int beg = offs[d], end = offs[d + 1];
        float a0 = 0.f, a1 = 0.f;
        int i = beg;
        for (; i + 4 <= end; i += 4) {
            u64 e0 = __builtin_nontemporal_load(&adj8[i]);
            u64 e1 = __builtin_nontemporal_load(&adj8[i + 1]);
            u64 e2 = __builtin_nontemporal_load(&adj8[i + 2]);
            u64 e3 = __builtin_nontemporal_load(&adj8[i + 3]);
            uint h0 = hbase[(size_t)(uint)e0 * 8 + col];
            uint h1 = hbase[(size_t)(uint)e1 * 8 + col];
            uint h2 = hbase[(size_t)(uint)e2 * 8 + col];
            uint h3 = hbase[(size_t)(uint)e3 * 8 + col];
            float w0 = __uint_as_float((uint)(e0 >> 32));
            float w1 = __uint_as_float((uint)(e1 >> 32));
            float w2 = __uint_as_float((uint)(e2 >> 32));
            float w3 = __uint_as_float((uint)(e3 >> 32));
            a0 = fmaf(w0, bflo(h0), a0); a1 = fmaf(w0, bfhi(h0), a1);
            a0 = fmaf(w1, bflo(h1), a0); a1 = fmaf(w1, bfhi(h1), a1);
            a0 = fmaf(w2, bflo(h2), a0); a1 = fmaf(w2, bfhi(h2), a1);
            a0 = fmaf(w3, bflo(h3), a0); a1 = fmaf(w3, bfhi(h3), a1);
        }
        for (; i < end; ++i) {
            u64 e = __builtin_nontemporal_load(&adj8[i]);
            uint hv = hbase[(size_t)(uint)e * 8 + col];
            float w = __uint_as_float((uint)(e >> 32));
            a0 = fmaf(w, bflo(hv), a0); a1 = fmaf(w, bfhi(hv), a1);
        }
        a0 += b0; a1 += b1;
        abase[(size_t)d * 8 + col] = bf16rne(a0) | (bf16rne(a1) << 16);
        ps0 += a0; pq0 += a0 * a0;
        ps1 += a1; pq1 += a1 * a1;
    }
    atomicAdd(&ls[col * 2], ps0);
    atomicAdd(&ls[col * 2 + 1], ps1);
    atomicAdd(&ls[16 + col * 2], pq0);
    atomicAdd(&ls[16 + col * 2 + 1], pq1);
    __syncthreads();
    if (tid < 16)      atomicAdd(&colsum[s * 16 + tid], ls[tid]);
    else if (tid < 32) atomicAdd(&colsum[128 + s * 16 + (tid - 16)], ls[tid]);
}

// ---------------- BN finalize: scale/shift, re-zero accumulators ----------

__global__ void k_bnfinal(float* __restrict__ colsum,
                          const float* __restrict__ g, const float* __restrict__ be,
                          float* __restrict__ scale, float* __restrict__ shift) {
    int t = threadIdx.x;  // 128
    float s = colsum[t], q = colsum[128 + t];
    float m = s * (1.0f / Nn);
    float var = q * (1.0f / Nn) - m * m;
    float istd = rsqrtf(var + EPSb);
    float sc = istd * g[t];
    scale[t] = sc;
    shift[t] = fmaf(-m, sc, be[t]);
    colsum[t] = 0.f;
    colsum[128 + t] = 0.f;
}

// ---------------- pool + linear (slice-major agg) -------------------------

__global__ __launch_bounds__(256) void k_pool(
    const uint* __restrict__ agg, const int* __restrict__ batch,
    const float* __restrict__ scale, const float* __restrict__ shift,
    const float* __restrict__ Wl, const float* __restrict__ bl,
    float* __restrict__ out) {
    int lane = threadIdx.x & 63;
    int g = (blockIdx.x * blockDim.x + threadIdx.x) >> 6;
    if (g >= Gg) return;
    int lo = 0, hi = Nn;
    while (lo < hi) { int mid = (lo + hi) >> 1; if (batch[mid] < g) lo = mid + 1; else hi = mid; }
    int beg = lo;
    hi = Nn;
    while (lo < hi) { int mid = (lo + hi) >> 1; if (batch[mid] < g + 1) lo = mid + 1; else hi = mid; }
    int end = lo;
    int sl = lane >> 3, j = lane & 7;
    int c0 = sl * 16 + j * 2;
    const uint* base = agg + (size_t)sl * Nn * 8 + j;
    float sc0 = scale[c0], sh0 = shift[c0];
    float sc1 = scale[c0 + 1], sh1 = shift[c0 + 1];
    float s0 = 0.f, s1 = 0.f;
    for (int n = beg; n < end; ++n) {
        uint v = base[(size_t)n * 8];
        s0 += fmaxf(fmaf(bflo(v), sc0, sh0), 0.f);
        s1 += fmaxf(fmaf(bfhi(v), sc1, sh1), 0.f);
    }
    float inv = 1.0f / fmaxf((float)(end - beg), 1.0f);
    float part = (s0 * inv) * Wl[c0] + (s1 * inv) * Wl[c0 + 1];
#pragma unroll
    for (int off = 32; off; off >>= 1) part += __shfl_down(part, off);
    if (lane == 0) out[g] = part + bl[0];
}

// ---------------- launch --------------------------------------------------

extern "C" void kernel_launch(void* const* d_in, const int* in_sizes, int n_in,
                              void* d_out, int out_size, void* d_ws, size_t ws_size,
                              hipStream_t stream) {
    const float* x   = (const float*)d_in[0];
    const int*   ei  = (const int*)d_in[1];
    const int*   src = ei;
    const int*   dst = ei + Ee;
    const int*   bat = (const int*)d_in[2];
    const float* W1 = (const float*)d_in[3];
    const float* b1 = (const float*)d_in[4];
    const float* g1 = (const float*)d_in[5];
    const float* be1 = (const float*)d_in[6];
    const float* W2 = (const float*)d_in[7];
    const float* b2 = (const float*)d_in[8];
    const float* g2 = (const float*)d_in[9];
    const float* be2 = (const float*)d_in[10];
    const float* W3 = (const float*)d_in[11];
    const float* b3 = (const float*)d_in[12];
    const float* g3 = (const float*)d_in[13];
    const float* be3 = (const float*)d_in[14];
    const float* Wl = (const float*)d_in[15];
    const float* bl = (const float*)d_in[16];
    float* out = (float*)d_out;

    char* w = (char*)d_ws;
    auto alloc = [&](size_t bytes) {
        void* p = (void*)w;
        w += (bytes + 255) & ~(size_t)255;
        return p;
    };
    int*   deg    = (int*)alloc((size_t)Nn * 4);
    int*   cursor = (int*)alloc((size_t)Nn * 4);
    int*   offs   = (int*)alloc((size_t)(Nn + 1) * 4);
    int*   bsum   = (int*)alloc(256 * 4);
    float* dinv   = (float*)alloc((size_t)Nn * 4);
    float* colsum = (float*)alloc(256 * 4);
    float* scale  = (float*)alloc(128 * 4);
    float* shift  = (float*)alloc(128 * 4);
    uint*  Wt1    = (uint*)alloc(128 * 64 * 4);
    uint*  Wt2    = (uint*)alloc(128 * 64 * 4);
    uint*  Wt3    = (uint*)alloc(128 * 64 * 4);
    int2*  adj    = (int2*)alloc((size_t)(Ee + Nn) * 8);
    uint*  tmp    = (uint*)alloc((size_t)Nn * 64 * 4);   // bf16-packed h, slice-major
    uint*  agg    = (uint*)alloc((size_t)Nn * 64 * 4);   // bf16-packed agg, slice-major

    // graph preprocessing + weight conversion
    k_init<<<(Nn + 255) / 256, 256, 0, stream>>>(deg, cursor, colsum);
    k_deg<<<(Ee + 255) / 256, 256, 0, stream>>>(dst, deg);
    k_dinv<<<(Nn + 255) / 256, 256, 0, stream>>>(deg, dinv);
    k_scan1<<<NB_SCAN, 256, 0, stream>>>(deg, bsum);
    k_scan2<<<1, 1, 0, stream>>>(bsum, NB_SCAN);
    k_scan3<<<NB_SCAN, 256, 0, stream>>>(deg, bsum, offs);
    k_fill<<<(Ee + Nn + 255) / 256, 256, 0, stream>>>(src, dst, offs, cursor, dinv, adj);
    k_wconv<<<32, 256, 0, stream>>>(W1, Wt1);
    k_wconv<<<32, 256, 0, stream>>>(W2, Wt2);
    k_wconv<<<32, 256, 0, stream>>>(W3, Wt3);
    // layer 1
    k_gemm<<<GEMM_BLOCKS, 256, 0, stream>>>(x, (const uint*)0, Wt1, scale, shift, tmp, 0);
    k_agg<<<AGG_BLOCKS, 256, 0, stream>>>(tmp, offs, adj, b1, agg, colsum);
    k_bnfinal<<<1, 128, 0, stream>>>(colsum, g1, be1, scale, shift);
    // layer 2
    k_gemm<<<GEMM_BLOCKS, 256, 0, stream>>>((const float*)0, agg, Wt2, scale, shift, tmp, 1);
    k_agg<<<AGG_BLOCKS, 256, 0, stream>>>(tmp, offs, adj, b2, agg, colsum);
    k_bnfinal<<<1, 128, 0, stream>>>(colsum, g2, be2, scale, shift);
    // layer 3
    k_gemm<<<GEMM_BLOCKS, 256, 0, stream>>>((const float*)0, agg, Wt3, scale, shift, tmp, 1);
    k_agg<<<AGG_BLOCKS, 256, 0, stream>>>(tmp, offs, adj, b3, agg, colsum);
    k_bnfinal<<<1, 128, 0, stream>>>(colsum, g3, be3, scale, shift);
    // pool + linear
    k_pool<<<(Gg * 64 + 255) / 256, 256, 0, stream>>>(agg, bat, scale, shift, Wl, bl, out);
}

// Round 6
// 682.801 us; speedup vs baseline: 1.5778x; 1.2646x over previous
//
#include <hip/hip_runtime.h>
#include <hip/hip_bf16.h>

#define Nn 100000
#define Ee 1600000
#define Hh 128
#define Gg 1000
#define EPSb 1e-5f

#define SCAN_CHUNK 1024
#define NB_SCAN 98          // ceil(100000/1024)
#define AGG_BLOCKS 2048
#define GEMM_BLOCKS 782     // ceil(100000/128)

typedef unsigned int uint;
typedef short short8 __attribute__((ext_vector_type(8)));
typedef float floatx4 __attribute__((ext_vector_type(4)));

// round-to-nearest-even f32 -> bf16 (as low 16 bits of return)
static __device__ __forceinline__ uint bf16rne(float f) {
    uint u = __float_as_uint(f);
    return (u + 0x7fffu + ((u >> 16) & 1u)) >> 16;
}
static __device__ __forceinline__ float bflo(uint u) { return __uint_as_float(u << 16); }
static __device__ __forceinline__ float bfhi(uint u) { return __uint_as_float(u & 0xffff0000u); }

// ---------------- graph preprocessing ----------------

__global__ void k_init(int* __restrict__ deg, int* __restrict__ cursor,
                       float* __restrict__ colsum) {
    int i = blockIdx.x * blockDim.x + threadIdx.x;
    if (i < Nn) { deg[i] = 1; cursor[i] = 0; }
    if (i < 768) colsum[i] = 0.f;   // 3 layers x (sum[128], sumsq[128])
}

__global__ void k_deg(const int* __restrict__ dst, int* __restrict__ deg) {
    int i = blockIdx.x * blockDim.x + threadIdx.x;
    if (i < Ee) atomicAdd(&deg[dst[i]], 1);
}

__global__ void k_scan1(const int* __restrict__ deg, int* __restrict__ bsum) {
    __shared__ int ls[256];
    int t = threadIdx.x;
    int base = blockIdx.x * SCAN_CHUNK + t * 4;
    int s = 0;
#pragma unroll
    for (int j = 0; j < 4; ++j) { int i = base + j; if (i < Nn) s += deg[i]; }
    ls[t] = s;
    __syncthreads();
    for (int off = 128; off; off >>= 1) {
        if (t < off) ls[t] += ls[t + off];
        __syncthreads();
    }
    if (t == 0) bsum[blockIdx.x] = ls[0];
}

__global__ void k_scan2(int* __restrict__ bsum, int nb) {
    int acc = 0;
    for (int b = 0; b < nb; ++b) { int v = bsum[b]; bsum[b] = acc; acc += v; }
}

// scan3 also emits dinv (folded k_dinv)
__global__ void k_scan3(const int* __restrict__ deg, const int* __restrict__ bsum,
                        int* __restrict__ offs, float* __restrict__ dinv) {
    __shared__ int ls[256];
    int t = threadIdx.x;
    int base = blockIdx.x * SCAN_CHUNK + t * 4;
    int d[4]; int s = 0;
#pragma unroll
    for (int j = 0; j < 4; ++j) {
        int i = base + j;
        d[j] = (i < Nn) ? deg[i] : 0;
        s += d[j];
    }
    ls[t] = s;
    __syncthreads();
    for (int off = 1; off < 256; off <<= 1) {
        int u = (t >= off) ? ls[t - off] : 0;
        __syncthreads();
        ls[t] += u;
        __syncthreads();
    }
    int run = bsum[blockIdx.x] + ls[t] - s;   // exclusive prefix for this thread
#pragma unroll
    for (int j = 0; j < 4; ++j) {
        int i = base + j;
        if (i < Nn) {
            offs[i] = run;
            dinv[i] = rsqrtf((float)d[j]);
        }
        run += d[j];
    }
    if (blockIdx.x == 0 && t == 0) offs[Nn] = Ee + Nn;
}

__global__ void k_fill(const int* __restrict__ src, const int* __restrict__ dst,
                       const int* __restrict__ offs, int* __restrict__ cursor,
                       const float* __restrict__ dinv,
                       int2* __restrict__ adj) {
    int i = blockIdx.x * blockDim.x + threadIdx.x;
    if (i >= Ee + Nn) return;
    int s, d;
    if (i < Ee) { s = src[i]; d = dst[i]; }
    else        { s = d = i - Ee; }
    int pos = offs[d] + atomicAdd(&cursor[d], 1);
    adj[pos] = make_int2(s, __float_as_int(dinv[s] * dinv[d]));
}

// ------- W conversion (all 3 layers): Wt[l][n][k/2] = bf16(W[k][n],W[k+1][n]) --

__global__ void k_wconv3(const float* __restrict__ W1, const float* __restrict__ W2,
                         const float* __restrict__ W3, uint* __restrict__ Wt) {
    int idx = blockIdx.x * blockDim.x + threadIdx.x;   // 3*8192
    if (idx >= 3 * 8192) return;
    const float* W = (idx < 8192) ? W1 : ((idx < 16384) ? W2 : W3);
    int k = idx & 8191;
    int n = k >> 6, ku = k & 63;
    uint lo = bf16rne(W[(size_t)(2 * ku) * 128 + n]);
    uint hi = bf16rne(W[(size_t)(2 * ku + 1) * 128 + n]);
    Wt[(size_t)(idx >> 13) * 8192 + n * 64 + ku] = lo | (hi << 16);
}

// ---------------- MFMA GEMM: tmp(bf16) = act(in) @ W ----------------------
// mode 0: in = fp32 x (row-major), identity activation.
// mode 1: in = row-major packed-bf16 agg; activation = relu(bn(v)) where the
// BN affine (scale/shift) is computed in-block from colsum + gamma + beta.

__global__ __launch_bounds__(256) void k_gemm(
    const float* __restrict__ inf, const uint* __restrict__ inb,
    const uint* __restrict__ Wtp,
    const float* __restrict__ cs, const float* __restrict__ gg,
    const float* __restrict__ be,
    uint* __restrict__ outb, int mode) {
    __shared__ uint XT[128][64];
    __shared__ uint WT[128][64];
    __shared__ float scsh[256];   // sc[128], sh[128]
    int t = threadIdx.x;
    int rowBase = blockIdx.x * 128;
    int r = t >> 1, half = t & 1;

    if (mode) {
        if (t < 128) {
            float s = cs[t], q = cs[128 + t];
            float m = s * (1.0f / Nn);
            float var = q * (1.0f / Nn) - m * m;
            float istd = rsqrtf(var + EPSb);
            float sc = istd * gg[t];
            scsh[t] = sc;
            scsh[128 + t] = fmaf(-m, sc, be[t]);
        }
        __syncthreads();
    }

    {   // stage activations
        int gr = rowBase + r;
        int grc = gr < Nn ? gr : Nn - 1;
        if (mode == 0) {
            const float* sp = inf + (size_t)grc * 128 + half * 64;
#pragma unroll
            for (int q = 0; q < 8; ++q) {
                float4 v0 = *(const float4*)(sp + q * 8);
                float4 v1 = *(const float4*)(sp + q * 8 + 4);
                uint4 o;
                o.x = bf16rne(v0.x) | (bf16rne(v0.y) << 16);
                o.y = bf16rne(v0.z) | (bf16rne(v0.w) << 16);
                o.z = bf16rne(v1.x) | (bf16rne(v1.y) << 16);
                o.w = bf16rne(v1.z) | (bf16rne(v1.w) << 16);
                int g = half * 8 + q;
                *(uint4*)&XT[r][(g ^ (r & 7)) << 2] = o;
            }
        } else {
            const uint* sp = inb + (size_t)grc * 64 + half * 32;
#pragma unroll
            for (int q = 0; q < 8; ++q) {
                uint4 v = *(const uint4*)(sp + q * 4);
                int fb = half * 64 + q * 8;
                float av[8] = {bflo(v.x), bfhi(v.x), bflo(v.y), bfhi(v.y),
                               bflo(v.z), bfhi(v.z), bflo(v.w), bfhi(v.w)};
                uint o[4];
#pragma unroll
                for (int k2 = 0; k2 < 4; ++k2) {
                    float lo = fmaxf(fmaf(av[2 * k2], scsh[fb + 2 * k2],
                                          scsh[128 + fb + 2 * k2]), 0.f);
                    float hi = fmaxf(fmaf(av[2 * k2 + 1], scsh[fb + 2 * k2 + 1],
                                          scsh[128 + fb + 2 * k2 + 1]), 0.f);
                    o[k2] = bf16rne(lo) | (bf16rne(hi) << 16);
                }
                uint4 ov = make_uint4(o[0], o[1], o[2], o[3]);
                int g = half * 8 + q;
                *(uint4*)&XT[r][(g ^ (r & 7)) << 2] = ov;
            }
        }
    }
    {   // stage W^T (already packed bf16)
        const uint* sp = Wtp + (size_t)r * 64 + half * 32;
#pragma unroll
        for (int q = 0; q < 8; ++q) {
            uint4 v = *(const uint4*)(sp + q * 4);
            int g = half * 8 + q;
            *(uint4*)&WT[r][(g ^ (r & 7)) << 2] = v;
        }
    }
    __syncthreads();

    int l = t & 63, w = t >> 6;
    int nb = (w >> 1) * 64;       // node-tile base
    int fb2 = (w & 1) * 64;       // feature-tile base
    int lr = l & 15, lk = l >> 4;
    floatx4 zero = {0.f, 0.f, 0.f, 0.f};
    floatx4 acc[4][4];
#pragma unroll
    for (int mi = 0; mi < 4; ++mi)
#pragma unroll
        for (int ni = 0; ni < 4; ++ni) acc[mi][ni] = zero;

#pragma unroll
    for (int kc = 0; kc < 4; ++kc) {
        short8 xf[4], wf[4];
        int g = kc * 4 + lk;
#pragma unroll
        for (int mi = 0; mi < 4; ++mi) {
            int rr = nb + mi * 16 + lr;
            xf[mi] = *(const short8*)&XT[rr][(g ^ (rr & 7)) << 2];
        }
#pragma unroll
        for (int ni = 0; ni < 4; ++ni) {
            int rr = fb2 + ni * 16 + lr;
            wf[ni] = *(const short8*)&WT[rr][(g ^ (rr & 7)) << 2];
        }
#pragma unroll
        for (int mi = 0; mi < 4; ++mi)
#pragma unroll
            for (int ni = 0; ni < 4; ++ni)
                acc[mi][ni] = __builtin_amdgcn_mfma_f32_16x16x32_bf16(
                    wf[ni], xf[mi], acc[mi][ni], 0, 0, 0);
    }

    // epilogue: D col(lane&15)=node, row((lane>>4)*4+reg)=feature
#pragma unroll
    for (int mi = 0; mi < 4; ++mi) {
        int node = rowBase + nb + mi * 16 + lr;
        if (node < Nn) {
            uint* op = outb + (size_t)node * 64;
#pragma unroll
            for (int ni = 0; ni < 4; ++ni) {
                int fo = fb2 + ni * 16 + lk * 4;
                uint2 o;
                o.x = bf16rne(acc[mi][ni][0]) | (bf16rne(acc[mi][ni][1]) << 16);
                o.y = bf16rne(acc[mi][ni][2]) | (bf16rne(acc[mi][ni][3]) << 16);
                *(uint2*)(op + (fo >> 1)) = o;
            }
        }
    }
}

// ------- aggregation: agg[d] = sum_e w*h[src] + bias; BN partials -------
// Row-major packed bf16 h (64 uints/row = 256B, one wave covers full row).
// 8-edge chunks, adjacency chunk for iteration k+1 prefetched during k's
// gather+fma; dual accumulator pairs to shorten fma chains.

__global__ __launch_bounds__(256) void k_agg(
    const uint* __restrict__ h32, const int* __restrict__ offs,
    const int2* __restrict__ adj,
    const float* __restrict__ bias, uint* __restrict__ agg,
    float* __restrict__ colsum) {
    __shared__ float ls[256];
    int tid = threadIdx.x;
    ls[tid] = 0.f;
    __syncthreads();
    int lane = tid & 63;
    int gw = blockIdx.x * 4 + (tid >> 6);
    int nw = AGG_BLOCKS * 4;
    int c0 = lane * 2;
    float bb0 = bias[c0], bb1 = bias[c0 + 1];
    float ps0 = 0.f, pq0 = 0.f, ps1 = 0.f, pq1 = 0.f;
    for (int d = gw; d < Nn; d += nw) {
        int beg = offs[d], end = offs[d + 1];
        float a0 = 0.f, a1 = 0.f, x0 = 0.f, x1 = 0.f;
        int i = beg;
        int nch = (end - beg) >> 3;
        if (nch > 0) {
            int2 e[8];
#pragma unroll
            for (int j = 0; j < 8; ++j) e[j] = adj[i + j];
            for (int ch = 1; ch < nch; ++ch) {
                uint hv[8];
#pragma unroll
                for (int j = 0; j < 8; ++j)
                    hv[j] = h32[(size_t)e[j].x * 64 + lane];
                int2 en[8];
#pragma unroll
                for (int j = 0; j < 8; ++j) en[j] = adj[i + 8 + j];
#pragma unroll
                for (int j = 0; j < 4; ++j) {
                    float w = __int_as_float(e[j].y);
                    a0 = fmaf(w, bflo(hv[j]), a0);
                    a1 = fmaf(w, bfhi(hv[j]), a1);
                }
#pragma unroll
                for (int j = 4; j < 8; ++j) {
                    float w = __int_as_float(e[j].y);
                    x0 = fmaf(w, bflo(hv[j]), x0);
                    x1 = fmaf(w, bfhi(hv[j]), x1);
                }
#pragma unroll
                for (int j = 0; j < 8; ++j) e[j] = en[j];
                i += 8;
            }
            {   // last full chunk (no prefetch)
                uint hv[8];
#pragma unroll
                for (int j = 0; j < 8; ++j)
                    hv[j] = h32[(size_t)e[j].x * 64 + lane];
#pragma unroll
                for (int j = 0; j < 4; ++j) {
                    float w = __int_as_float(e[j].y);
                    a0 = fmaf(w, bflo(hv[j]), a0);
                    a1 = fmaf(w, bfhi(hv[j]), a1);
                }
#pragma unroll
                for (int j = 4; j < 8; ++j) {
                    float w = __int_as_float(e[j].y);
                    x0 = fmaf(w, bflo(hv[j]), x0);
                    x1 = fmaf(w, bfhi(hv[j]), x1);
                }
                i += 8;
            }
        }
        for (; i < end; ++i) {
            int2 e = adj[i];
            uint hv = h32[(size_t)e.x * 64 + lane];
            float w = __int_as_float(e.y);
            a0 = fmaf(w, bflo(hv), a0);
            a1 = fmaf(w, bfhi(hv), a1);
        }
        a0 += x0 + bb0;
        a1 += x1 + bb1;
        agg[(size_t)d * 64 + lane] = bf16rne(a0) | (bf16rne(a1) << 16);
        ps0 += a0; pq0 += a0 * a0;
        ps1 += a1; pq1 += a1 * a1;
    }
    atomicAdd(&ls[c0], ps0);
    atomicAdd(&ls[c0 + 1], ps1);
    atomicAdd(&ls[128 + c0], pq0);
    atomicAdd(&ls[128 + c0 + 1], pq1);
    __syncthreads();
    atomicAdd(&colsum[tid], ls[tid]);
}

// ---------------- pool + linear (BN affine computed in-block) -------------

__global__ __launch_bounds__(256) void k_pool(
    const uint* __restrict__ agg, const int* __restrict__ batch,
    const float* __restrict__ cs, const float* __restrict__ gg,
    const float* __restrict__ be,
    const float* __restrict__ Wl, const float* __restrict__ bl,
    float* __restrict__ out) {
    __shared__ float scsh[256];
    int tid = threadIdx.x;
    if (tid < 128) {
        float s = cs[tid], q = cs[128 + tid];
        float m = s * (1.0f / Nn);
        float var = q * (1.0f / Nn) - m * m;
        float istd = rsqrtf(var + EPSb);
        float sc = istd * gg[tid];
        scsh[tid] = sc;
        scsh[128 + tid] = fmaf(-m, sc, be[tid]);
    }
    __syncthreads();
    int lane = tid & 63;
    int g = (blockIdx.x * blockDim.x + tid) >> 6;
    if (g >= Gg) return;
    int lo = 0, hi = Nn;
    while (lo < hi) { int mid = (lo + hi) >> 1; if (batch[mid] < g) lo = mid + 1; else hi = mid; }
    int beg = lo;
    hi = Nn;
    while (lo < hi) { int mid = (lo + hi) >> 1; if (batch[mid] < g + 1) lo = mid + 1; else hi = mid; }
    int end = lo;
    int c0 = lane * 2;
    float sc0 = scsh[c0], sh0 = scsh[128 + c0];
    float sc1 = scsh[c0 + 1], sh1 = scsh[128 + c0 + 1];
    float s0 = 0.f, s1 = 0.f;
    for (int n = beg; n < end; ++n) {
        uint v = agg[(size_t)n * 64 + lane];
        s0 += fmaxf(fmaf(bflo(v), sc0, sh0), 0.f);
        s1 += fmaxf(fmaf(bfhi(v), sc1, sh1), 0.f);
    }
    float inv = 1.0f / fmaxf((float)(end - beg), 1.0f);
    float part = (s0 * inv) * Wl[c0] + (s1 * inv) * Wl[c0 + 1];
#pragma unroll
    for (int off = 32; off; off >>= 1) part += __shfl_down(part, off);
    if (lane == 0) out[g] = part + bl[0];
}

// ---------------- launch --------------------------------------------------

extern "C" void kernel_launch(void* const* d_in, const int* in_sizes, int n_in,
                              void* d_out, int out_size, void* d_ws, size_t ws_size,
                              hipStream_t stream) {
    const float* x   = (const float*)d_in[0];
    const int*   ei  = (const int*)d_in[1];
    const int*   src = ei;
    const int*   dst = ei + Ee;
    const int*   bat = (const int*)d_in[2];
    const float* W1 = (const float*)d_in[3];
    const float* b1 = (const float*)d_in[4];
    const float* g1 = (const float*)d_in[5];
    const float* be1 = (const float*)d_in[6];
    const float* W2 = (const float*)d_in[7];
    const float* b2 = (const float*)d_in[8];
    const float* g2 = (const float*)d_in[9];
    const float* be2 = (const float*)d_in[10];
    const float* W3 = (const float*)d_in[11];
    const float* b3 = (const float*)d_in[12];
    const float* g3 = (const float*)d_in[13];
    const float* be3 = (const float*)d_in[14];
    const float* Wl = (const float*)d_in[15];
    const float* bl = (const float*)d_in[16];
    float* out = (float*)d_out;

    char* w = (char*)d_ws;
    auto alloc = [&](size_t bytes) {
        void* p = (void*)w;
        w += (bytes + 255) & ~(size_t)255;
        return p;
    };
    int*   deg    = (int*)alloc((size_t)Nn * 4);
    int*   cursor = (int*)alloc((size_t)Nn * 4);
    int*   offs   = (int*)alloc((size_t)(Nn + 1) * 4);
    int*   bsum   = (int*)alloc(256 * 4);
    float* dinv   = (float*)alloc((size_t)Nn * 4);
    float* colsum = (float*)alloc(768 * 4);   // 3 layers x 256
    uint*  Wt     = (uint*)alloc((size_t)3 * 8192 * 4);
    int2*  adj    = (int2*)alloc((size_t)(Ee + Nn) * 8);
    uint*  tmp    = (uint*)alloc((size_t)Nn * 64 * 4);   // bf16-packed h
    uint*  agg    = (uint*)alloc((size_t)Nn * 64 * 4);   // bf16-packed agg

    float* csA = colsum;        // stats of agg1 (uses g1/be1)
    float* csB = colsum + 256;  // stats of agg2 (uses g2/be2)
    float* csC = colsum + 512;  // stats of agg3 (uses g3/be3)

    // graph preprocessing + weight conversion
    k_init<<<(Nn + 255) / 256, 256, 0, stream>>>(deg, cursor, colsum);
    k_deg<<<(Ee + 255) / 256, 256, 0, stream>>>(dst, deg);
    k_scan1<<<NB_SCAN, 256, 0, stream>>>(deg, bsum);
    k_scan2<<<1, 1, 0, stream>>>(bsum, NB_SCAN);
    k_scan3<<<NB_SCAN, 256, 0, stream>>>(deg, bsum, offs, dinv);
    k_fill<<<(Ee + Nn + 255) / 256, 256, 0, stream>>>(src, dst, offs, cursor, dinv, adj);
    k_wconv3<<<96, 256, 0, stream>>>(W1, W2, W3, Wt);
    // layer 1
    k_gemm<<<GEMM_BLOCKS, 256, 0, stream>>>(x, (const uint*)0, Wt,
                                            (const float*)0, (const float*)0,
                                            (const float*)0, tmp, 0);
    k_agg<<<AGG_BLOCKS, 256, 0, stream>>>(tmp, offs, adj, b1, agg, csA);
    // layer 2
    k_gemm<<<GEMM_BLOCKS, 256, 0, stream>>>((const float*)0, agg, Wt + 8192,
                                            csA, g1, be1, tmp, 1);
    k_agg<<<AGG_BLOCKS, 256, 0, stream>>>(tmp, offs, adj, b2, agg, csB);
    // layer 3
    k_gemm<<<GEMM_BLOCKS, 256, 0, stream>>>((const float*)0, agg, Wt + 16384,
                                            csB, g2, be2, tmp, 1);
    k_agg<<<AGG_BLOCKS, 256, 0, stream>>>(tmp, offs, adj, b3, agg, csC);
    // pool + linear
    k_pool<<<(Gg * 64 + 255) / 256, 256, 0, stream>>>(agg, bat, csC, g3, be3,
                                                      Wl, bl, out);
}

// Round 7
// 598.468 us; speedup vs baseline: 1.8001x; 1.1409x over previous
//
#include <hip/hip_runtime.h>
#include <hip/hip_bf16.h>

#define Nn 100000
#define Ee 1600000
#define Hh 128
#define Gg 1000
#define EPSb 1e-5f

#define SCAN_CHUNK 1024
#define NB_SCAN 98          // ceil(100000/1024)
#define AGG_BLOCKS 2048
#define GEMM_BLOCKS 782     // ceil(100000/128)

typedef unsigned int uint;
typedef short short8 __attribute__((ext_vector_type(8)));
typedef float floatx4 __attribute__((ext_vector_type(4)));

// round-to-nearest-even f32 -> bf16 (as low 16 bits of return)
static __device__ __forceinline__ uint bf16rne(float f) {
    uint u = __float_as_uint(f);
    return (u + 0x7fffu + ((u >> 16) & 1u)) >> 16;
}
static __device__ __forceinline__ float bflo(uint u) { return __uint_as_float(u << 16); }
static __device__ __forceinline__ float bfhi(uint u) { return __uint_as_float(u & 0xffff0000u); }

// ---------------- graph preprocessing ----------------

__global__ void k_init(int* __restrict__ deg, int* __restrict__ cursor,
                       float* __restrict__ colsum) {
    int i = blockIdx.x * blockDim.x + threadIdx.x;
    if (i < Nn) { deg[i] = 1; cursor[i] = 0; }
    if (i < 768) colsum[i] = 0.f;   // 3 layers x (sum[128], sumsq[128])
}

__global__ void k_deg(const int* __restrict__ dst, int* __restrict__ deg) {
    int i = blockIdx.x * blockDim.x + threadIdx.x;
    if (i < Ee) atomicAdd(&deg[dst[i]], 1);
}

__global__ void k_scan1(const int* __restrict__ deg, int* __restrict__ bsum) {
    __shared__ int ls[256];
    int t = threadIdx.x;
    int base = blockIdx.x * SCAN_CHUNK + t * 4;
    int s = 0;
#pragma unroll
    for (int j = 0; j < 4; ++j) { int i = base + j; if (i < Nn) s += deg[i]; }
    ls[t] = s;
    __syncthreads();
    for (int off = 128; off; off >>= 1) {
        if (t < off) ls[t] += ls[t + off];
        __syncthreads();
    }
    if (t == 0) bsum[blockIdx.x] = ls[0];
}

// parallel exclusive scan over NB_SCAN block sums (single block, 128 thr)
__global__ void k_scan2(int* __restrict__ bsum) {
    __shared__ int ls[128];
    int t = threadIdx.x;
    int v = (t < NB_SCAN) ? bsum[t] : 0;
    ls[t] = v;
    __syncthreads();
    for (int off = 1; off < 128; off <<= 1) {
        int u = (t >= off) ? ls[t - off] : 0;
        __syncthreads();
        ls[t] += u;
        __syncthreads();
    }
    if (t < NB_SCAN) bsum[t] = ls[t] - v;
}

// scan3 also emits dinv (folded k_dinv)
__global__ void k_scan3(const int* __restrict__ deg, const int* __restrict__ bsum,
                        int* __restrict__ offs, float* __restrict__ dinv) {
    __shared__ int ls[256];
    int t = threadIdx.x;
    int base = blockIdx.x * SCAN_CHUNK + t * 4;
    int d[4]; int s = 0;
#pragma unroll
    for (int j = 0; j < 4; ++j) {
        int i = base + j;
        d[j] = (i < Nn) ? deg[i] : 0;
        s += d[j];
    }
    ls[t] = s;
    __syncthreads();
    for (int off = 1; off < 256; off <<= 1) {
        int u = (t >= off) ? ls[t - off] : 0;
        __syncthreads();
        ls[t] += u;
        __syncthreads();
    }
    int run = bsum[blockIdx.x] + ls[t] - s;   // exclusive prefix for this thread
#pragma unroll
    for (int j = 0; j < 4; ++j) {
        int i = base + j;
        if (i < Nn) {
            offs[i] = run;
            dinv[i] = rsqrtf((float)d[j]);
        }
        run += d[j];
    }
    if (blockIdx.x == 0 && t == 0) offs[Nn] = Ee + Nn;
}

__global__ void k_fill(const int* __restrict__ src, const int* __restrict__ dst,
                       const int* __restrict__ offs, int* __restrict__ cursor,
                       const float* __restrict__ dinv,
                       int2* __restrict__ adj) {
    int i = blockIdx.x * blockDim.x + threadIdx.x;
    if (i >= Ee + Nn) return;
    int s, d;
    if (i < Ee) { s = src[i]; d = dst[i]; }
    else        { s = d = i - Ee; }
    int pos = offs[d] + atomicAdd(&cursor[d], 1);
    adj[pos] = make_int2(s, __float_as_int(dinv[s] * dinv[d]));
}

// ------- W conversion (all 3 layers): Wt[l][n][k/2] = bf16(W[k][n],W[k+1][n]) --

__global__ void k_wconv3(const float* __restrict__ W1, const float* __restrict__ W2,
                         const float* __restrict__ W3, uint* __restrict__ Wt) {
    int idx = blockIdx.x * blockDim.x + threadIdx.x;   // 3*8192
    if (idx >= 3 * 8192) return;
    const float* W = (idx < 8192) ? W1 : ((idx < 16384) ? W2 : W3);
    int k = idx & 8191;
    int n = k >> 6, ku = k & 63;
    uint lo = bf16rne(W[(size_t)(2 * ku) * 128 + n]);
    uint hi = bf16rne(W[(size_t)(2 * ku + 1) * 128 + n]);
    Wt[(size_t)(idx >> 13) * 8192 + n * 64 + ku] = lo | (hi << 16);
}

// ---------------- MFMA GEMM: tmp(bf16) = act(in) @ W ----------------------
// mode 0: in = fp32 x (row-major), identity activation.
// mode 1: in = row-major packed-bf16 agg; activation = relu(bn(v)) where the
// BN affine (scale/shift) is computed in-block from colsum + gamma + beta.

__global__ __launch_bounds__(256) void k_gemm(
    const float* __restrict__ inf, const uint* __restrict__ inb,
    const uint* __restrict__ Wtp,
    const float* __restrict__ cs, const float* __restrict__ gg,
    const float* __restrict__ be,
    uint* __restrict__ outb, int mode) {
    __shared__ uint XT[128][64];
    __shared__ uint WT[128][64];
    __shared__ float scsh[256];   // sc[128], sh[128]
    int t = threadIdx.x;
    int rowBase = blockIdx.x * 128;
    int r = t >> 1, half = t & 1;

    if (mode) {
        if (t < 128) {
            float s = cs[t], q = cs[128 + t];
            float m = s * (1.0f / Nn);
            float var = q * (1.0f / Nn) - m * m;
            float istd = rsqrtf(var + EPSb);
            float sc = istd * gg[t];
            scsh[t] = sc;
            scsh[128 + t] = fmaf(-m, sc, be[t]);
        }
        __syncthreads();
    }

    {   // stage activations
        int gr = rowBase + r;
        int grc = gr < Nn ? gr : Nn - 1;
        if (mode == 0) {
            const float* sp = inf + (size_t)grc * 128 + half * 64;
#pragma unroll
            for (int q = 0; q < 8; ++q) {
                float4 v0 = *(const float4*)(sp + q * 8);
                float4 v1 = *(const float4*)(sp + q * 8 + 4);
                uint4 o;
                o.x = bf16rne(v0.x) | (bf16rne(v0.y) << 16);
                o.y = bf16rne(v0.z) | (bf16rne(v0.w) << 16);
                o.z = bf16rne(v1.x) | (bf16rne(v1.y) << 16);
                o.w = bf16rne(v1.z) | (bf16rne(v1.w) << 16);
                int g = half * 8 + q;
                *(uint4*)&XT[r][(g ^ (r & 7)) << 2] = o;
            }
        } else {
            const uint* sp = inb + (size_t)grc * 64 + half * 32;
#pragma unroll
            for (int q = 0; q < 8; ++q) {
                uint4 v = *(const uint4*)(sp + q * 4);
                int fb = half * 64 + q * 8;
                float av[8] = {bflo(v.x), bfhi(v.x), bflo(v.y), bfhi(v.y),
                               bflo(v.z), bfhi(v.z), bflo(v.w), bfhi(v.w)};
                uint o[4];
#pragma unroll
                for (int k2 = 0; k2 < 4; ++k2) {
                    float lo = fmaxf(fmaf(av[2 * k2], scsh[fb + 2 * k2],
                                          scsh[128 + fb + 2 * k2]), 0.f);
                    float hi = fmaxf(fmaf(av[2 * k2 + 1], scsh[fb + 2 * k2 + 1],
                                          scsh[128 + fb + 2 * k2 + 1]), 0.f);
                    o[k2] = bf16rne(lo) | (bf16rne(hi) << 16);
                }
                uint4 ov = make_uint4(o[0], o[1], o[2], o[3]);
                int g = half * 8 + q;
                *(uint4*)&XT[r][(g ^ (r & 7)) << 2] = ov;
            }
        }
    }
    {   // stage W^T (already packed bf16)
        const uint* sp = Wtp + (size_t)r * 64 + half * 32;
#pragma unroll
        for (int q = 0; q < 8; ++q) {
            uint4 v = *(const uint4*)(sp + q * 4);
            int g = half * 8 + q;
            *(uint4*)&WT[r][(g ^ (r & 7)) << 2] = v;
        }
    }
    __syncthreads();

    int l = t & 63, w = t >> 6;
    int nb = (w >> 1) * 64;       // node-tile base
    int fb2 = (w & 1) * 64;       // feature-tile base
    int lr = l & 15, lk = l >> 4;
    floatx4 zero = {0.f, 0.f, 0.f, 0.f};
    floatx4 acc[4][4];
#pragma unroll
    for (int mi = 0; mi < 4; ++mi)
#pragma unroll
        for (int ni = 0; ni < 4; ++ni) acc[mi][ni] = zero;

#pragma unroll
    for (int kc = 0; kc < 4; ++kc) {
        short8 xf[4], wf[4];
        int g = kc * 4 + lk;
#pragma unroll
        for (int mi = 0; mi < 4; ++mi) {
            int rr = nb + mi * 16 + lr;
            xf[mi] = *(const short8*)&XT[rr][(g ^ (rr & 7)) << 2];
        }
#pragma unroll
        for (int ni = 0; ni < 4; ++ni) {
            int rr = fb2 + ni * 16 + lr;
            wf[ni] = *(const short8*)&WT[rr][(g ^ (rr & 7)) << 2];
        }
#pragma unroll
        for (int mi = 0; mi < 4; ++mi)
#pragma unroll
            for (int ni = 0; ni < 4; ++ni)
                acc[mi][ni] = __builtin_amdgcn_mfma_f32_16x16x32_bf16(
                    wf[ni], xf[mi], acc[mi][ni], 0, 0, 0);
    }

    // epilogue: D col(lane&15)=node, row((lane>>4)*4+reg)=feature
#pragma unroll
    for (int mi = 0; mi < 4; ++mi) {
        int node = rowBase + nb + mi * 16 + lr;
        if (node < Nn) {
            uint* op = outb + (size_t)node * 64;
#pragma unroll
            for (int ni = 0; ni < 4; ++ni) {
                int fo = fb2 + ni * 16 + lk * 4;
                uint2 o;
                o.x = bf16rne(acc[mi][ni][0]) | (bf16rne(acc[mi][ni][1]) << 16);
                o.y = bf16rne(acc[mi][ni][2]) | (bf16rne(acc[mi][ni][3]) << 16);
                *(uint2*)(op + (fo >> 1)) = o;
            }
        }
    }
}

// ------- aggregation: agg[d] = sum_e w*h[src] + bias; BN partials -------
// Round-3-proven loop: 8x unrolled, compiler-scheduled, no manual prefetch.

__global__ __launch_bounds__(256) void k_agg(
    const uint* __restrict__ h32, const int* __restrict__ offs,
    const int2* __restrict__ adj,
    const float* __restrict__ bias, uint* __restrict__ agg,
    float* __restrict__ colsum) {
    __shared__ float ls[256];
    int tid = threadIdx.x;
    ls[tid] = 0.f;
    __syncthreads();
    int lane = tid & 63;
    int gw = blockIdx.x * 4 + (tid >> 6);
    int nw = AGG_BLOCKS * 4;
    int c0 = lane * 2;
    float b0 = bias[c0], b1 = bias[c0 + 1];
    float ps0 = 0.f, pq0 = 0.f, ps1 = 0.f, pq1 = 0.f;
    for (int d = gw; d < Nn; d += nw) {
        int beg = offs[d], end = offs[d + 1];
        float a0 = 0.f, a1 = 0.f;
        int i = beg;
        for (; i + 8 <= end; i += 8) {
            int2 e[8];
#pragma unroll
            for (int j = 0; j < 8; ++j) e[j] = adj[i + j];
            uint hv[8];
#pragma unroll
            for (int j = 0; j < 8; ++j)
                hv[j] = h32[(size_t)e[j].x * 64 + lane];
#pragma unroll
            for (int j = 0; j < 8; ++j) {
                float w = __int_as_float(e[j].y);
                a0 = fmaf(w, bflo(hv[j]), a0);
                a1 = fmaf(w, bfhi(hv[j]), a1);
            }
        }
        for (; i < end; ++i) {
            int2 e = adj[i];
            uint hv = h32[(size_t)e.x * 64 + lane];
            float w = __int_as_float(e.y);
            a0 = fmaf(w, bflo(hv), a0);
            a1 = fmaf(w, bfhi(hv), a1);
        }
        a0 += b0; a1 += b1;
        agg[(size_t)d * 64 + lane] = bf16rne(a0) | (bf16rne(a1) << 16);
        ps0 += a0; pq0 += a0 * a0;
        ps1 += a1; pq1 += a1 * a1;
    }
    atomicAdd(&ls[c0], ps0);
    atomicAdd(&ls[c0 + 1], ps1);
    atomicAdd(&ls[128 + c0], pq0);
    atomicAdd(&ls[128 + c0 + 1], pq1);
    __syncthreads();
    atomicAdd(&colsum[tid], ls[tid]);
}

// ---------------- pool + linear (BN affine computed in-block) -------------

__global__ __launch_bounds__(256) void k_pool(
    const uint* __restrict__ agg, const int* __restrict__ batch,
    const float* __restrict__ cs, const float* __restrict__ gg,
    const float* __restrict__ be,
    const float* __restrict__ Wl, const float* __restrict__ bl,
    float* __restrict__ out) {
    __shared__ float scsh[256];
    int tid = threadIdx.x;
    if (tid < 128) {
        float s = cs[tid], q = cs[128 + tid];
        float m = s * (1.0f / Nn);
        float var = q * (1.0f / Nn) - m * m;
        float istd = rsqrtf(var + EPSb);
        float sc = istd * gg[tid];
        scsh[tid] = sc;
        scsh[128 + tid] = fmaf(-m, sc, be[tid]);
    }
    __syncthreads();
    int lane = tid & 63;
    int g = (blockIdx.x * blockDim.x + tid) >> 6;
    if (g >= Gg) return;
    int lo = 0, hi = Nn;
    while (lo < hi) { int mid = (lo + hi) >> 1; if (batch[mid] < g) lo = mid + 1; else hi = mid; }
    int beg = lo;
    hi = Nn;
    while (lo < hi) { int mid = (lo + hi) >> 1; if (batch[mid] < g + 1) lo = mid + 1; else hi = mid; }
    int end = lo;
    int c0 = lane * 2;
    float sc0 = scsh[c0], sh0 = scsh[128 + c0];
    float sc1 = scsh[c0 + 1], sh1 = scsh[128 + c0 + 1];
    float s0 = 0.f, s1 = 0.f;
    for (int n = beg; n < end; ++n) {
        uint v = agg[(size_t)n * 64 + lane];
        s0 += fmaxf(fmaf(bflo(v), sc0, sh0), 0.f);
        s1 += fmaxf(fmaf(bfhi(v), sc1, sh1), 0.f);
    }
    float inv = 1.0f / fmaxf((float)(end - beg), 1.0f);
    float part = (s0 * inv) * Wl[c0] + (s1 * inv) * Wl[c0 + 1];
#pragma unroll
    for (int off = 32; off; off >>= 1) part += __shfl_down(part, off);
    if (lane == 0) out[g] = part + bl[0];
}

// ---------------- launch --------------------------------------------------

extern "C" void kernel_launch(void* const* d_in, const int* in_sizes, int n_in,
                              void* d_out, int out_size, void* d_ws, size_t ws_size,
                              hipStream_t stream) {
    const float* x   = (const float*)d_in[0];
    const int*   ei  = (const int*)d_in[1];
    const int*   src = ei;
    const int*   dst = ei + Ee;
    const int*   bat = (const int*)d_in[2];
    const float* W1 = (const float*)d_in[3];
    const float* b1 = (const float*)d_in[4];
    const float* g1 = (const float*)d_in[5];
    const float* be1 = (const float*)d_in[6];
    const float* W2 = (const float*)d_in[7];
    const float* b2 = (const float*)d_in[8];
    const float* g2 = (const float*)d_in[9];
    const float* be2 = (const float*)d_in[10];
    const float* W3 = (const float*)d_in[11];
    const float* b3 = (const float*)d_in[12];
    const float* g3 = (const float*)d_in[13];
    const float* be3 = (const float*)d_in[14];
    const float* Wl = (const float*)d_in[15];
    const float* bl = (const float*)d_in[16];
    float* out = (float*)d_out;

    char* w = (char*)d_ws;
    auto alloc = [&](size_t bytes) {
        void* p = (void*)w;
        w += (bytes + 255) & ~(size_t)255;
        return p;
    };
    int*   deg    = (int*)alloc((size_t)Nn * 4);
    int*   cursor = (int*)alloc((size_t)Nn * 4);
    int*   offs   = (int*)alloc((size_t)(Nn + 1) * 4);
    int*   bsum   = (int*)alloc(256 * 4);
    float* dinv   = (float*)alloc((size_t)Nn * 4);
    float* colsum = (float*)alloc(768 * 4);   // 3 layers x 256
    uint*  Wt     = (uint*)alloc((size_t)3 * 8192 * 4);
    int2*  adj    = (int2*)alloc((size_t)(Ee + Nn) * 8);
    uint*  tmp    = (uint*)alloc((size_t)Nn * 64 * 4);   // bf16-packed h
    uint*  agg    = (uint*)alloc((size_t)Nn * 64 * 4);   // bf16-packed agg

    float* csA = colsum;        // stats of agg1 (uses g1/be1)
    float* csB = colsum + 256;  // stats of agg2 (uses g2/be2)
    float* csC = colsum + 512;  // stats of agg3 (uses g3/be3)

    // graph preprocessing + weight conversion
    k_init<<<(Nn + 255) / 256, 256, 0, stream>>>(deg, cursor, colsum);
    k_deg<<<(Ee + 255) / 256, 256, 0, stream>>>(dst, deg);
    k_scan1<<<NB_SCAN, 256, 0, stream>>>(deg, bsum);
    k_scan2<<<1, 128, 0, stream>>>(bsum);
    k_scan3<<<NB_SCAN, 256, 0, stream>>>(deg, bsum, offs, dinv);
    k_fill<<<(Ee + Nn + 255) / 256, 256, 0, stream>>>(src, dst, offs, cursor, dinv, adj);
    k_wconv3<<<96, 256, 0, stream>>>(W1, W2, W3, Wt);
    // layer 1
    k_gemm<<<GEMM_BLOCKS, 256, 0, stream>>>(x, (const uint*)0, Wt,
                                            (const float*)0, (const float*)0,
                                            (const float*)0, tmp, 0);
    k_agg<<<AGG_BLOCKS, 256, 0, stream>>>(tmp, offs, adj, b1, agg, csA);
    // layer 2
    k_gemm<<<GEMM_BLOCKS, 256, 0, stream>>>((const float*)0, agg, Wt + 8192,
                                            csA, g1, be1, tmp, 1);
    k_agg<<<AGG_BLOCKS, 256, 0, stream>>>(tmp, offs, adj, b2, agg, csB);
    // layer 3
    k_gemm<<<GEMM_BLOCKS, 256, 0, stream>>>((const float*)0, agg, Wt + 16384,
                                            csB, g2, be2, tmp, 1);
    k_agg<<<AGG_BLOCKS, 256, 0, stream>>>(tmp, offs, adj, b3, agg, csC);
    // pool + linear
    k_pool<<<(Gg * 64 + 255) / 256, 256, 0, stream>>>(agg, bat, csC, g3, be3,
                                                      Wl, bl, out);
}